// Round 2
// baseline (262.601 us; speedup 1.0000x reference)
//
#include <hip/hip_runtime.h>

// Antecedents: out[n, r] = prod_v memberships[v, n, s_v(r)]
// r = s0*4^5 + s1*4^4 + s2*4^3 + s3*4^2 + s4*4 + s5  (s5 fastest)
//
// memberships layout: [N_VARS=6, N_SAMPLES=16384, N_SETS=4] fp32
// output: [16384, 4096] fp32 = 268 MB  -> write-BW bound (~43 us roofline)

constexpr int N_VARS    = 6;
constexpr int N_SAMPLES = 16384;
constexpr int N_SETS    = 4;
constexpr int N_COMBOS  = 1024;  // 4^5 combos of s0..s4; s5 handled by float4

// Native vector type — __builtin_nontemporal_store rejects HIP_vector_type.
typedef float v4f __attribute__((ext_vector_type(4)));

__global__ __launch_bounds__(256) void antecedents_kernel(
    const float* __restrict__ m, v4f* __restrict__ out4) {
  const int n = blockIdx.x;   // sample
  const int t = threadIdx.x;  // 0..255

  // Stage this sample's 24 membership values into LDS (broadcast to all lanes).
  __shared__ __align__(16) float sm[N_VARS][N_SETS];
  if (t < N_VARS * N_SETS) {
    const int v = t >> 2, s = t & 3;
    sm[v][s] = m[(size_t)v * (N_SAMPLES * N_SETS) + (size_t)n * N_SETS + s];
  }
  __syncthreads();

  // Per-thread fixed set indices for vars 1..4 (c = i*256 + t, t<256 so
  // s0 == i exactly, and s1..s4 depend only on t).
  const int s1 = (t >> 6) & 3;
  const int s2 = (t >> 4) & 3;
  const int s3 = (t >> 2) & 3;
  const int s4 = t & 3;

  const float q = sm[1][s1] * sm[2][s2] * sm[3][s3] * sm[4][s4];
  const v4f m5 = *reinterpret_cast<const v4f*>(&sm[5][0]);

  v4f* dst = out4 + (size_t)n * N_COMBOS + t;
#pragma unroll
  for (int i = 0; i < 4; ++i) {
    const float p = sm[0][i] * q;
    const v4f val = p * m5;  // elementwise on ext_vector_type
    // Output is streamed (never re-read): bypass L2 allocation.
    __builtin_nontemporal_store(val, dst + i * 256);
  }
}

extern "C" void kernel_launch(void* const* d_in, const int* in_sizes, int n_in,
                              void* d_out, int out_size, void* d_ws, size_t ws_size,
                              hipStream_t stream) {
  const float* m = (const float*)d_in[0];
  v4f* out = (v4f*)d_out;
  antecedents_kernel<<<N_SAMPLES, 256, 0, stream>>>(m, out);
}

// Round 3
// 256.648 us; speedup vs baseline: 1.0232x; 1.0232x over previous
//
#include <hip/hip_runtime.h>

// Antecedents: out[n, r] = prod_v memberships[v, n, s_v(r)]
// r = s0*4^5 + s1*4^4 + s2*4^3 + s3*4^2 + s4*4 + s5  (s5 fastest)
//
// memberships layout: [N_VARS=6, N_SAMPLES=16384, N_SETS=4] fp32
// output: [16384, 4096] fp32 = 268 MB  -> write-BW bound (~43 us roofline)
//
// R2 post-mortem: nontemporal (`nt`) stores bypassed L2 write-combining and
// capped us at 1.0 TB/s; the harness's own fillBuffer (plain stores) hits
// 6.4 TB/s on the same path. Plain stores here.

constexpr int N_VARS    = 6;
constexpr int N_SAMPLES = 16384;
constexpr int N_SETS    = 4;
constexpr int N_COMBOS  = 1024;  // 4^5 combos of s0..s4; s5 handled by float4

typedef float v4f __attribute__((ext_vector_type(4)));

__global__ __launch_bounds__(256) void antecedents_kernel(
    const float* __restrict__ m, v4f* __restrict__ out4) {
  const int n = blockIdx.x;   // sample
  const int t = threadIdx.x;  // 0..255

  // Stage this sample's 24 membership values into LDS (broadcast to all lanes).
  __shared__ __align__(16) float sm[N_VARS][N_SETS];
  if (t < N_VARS * N_SETS) {
    const int v = t >> 2, s = t & 3;
    sm[v][s] = m[(size_t)v * (N_SAMPLES * N_SETS) + (size_t)n * N_SETS + s];
  }
  __syncthreads();

  // Per-thread fixed set indices for vars 1..4 (c = i*256 + t, t<256 so
  // s0 == i exactly, and s1..s4 depend only on t).
  const int s1 = (t >> 6) & 3;
  const int s2 = (t >> 4) & 3;
  const int s3 = (t >> 2) & 3;
  const int s4 = t & 3;

  const float q = sm[1][s1] * sm[2][s2] * sm[3][s3] * sm[4][s4];
  const v4f m5 = *reinterpret_cast<const v4f*>(&sm[5][0]);

  v4f* dst = out4 + (size_t)n * N_COMBOS + t;
#pragma unroll
  for (int i = 0; i < 4; ++i) {
    const float p = sm[0][i] * q;
    dst[i * 256] = p * m5;  // plain coalesced 16B/lane stores via L2
  }
}

extern "C" void kernel_launch(void* const* d_in, const int* in_sizes, int n_in,
                              void* d_out, int out_size, void* d_ws, size_t ws_size,
                              hipStream_t stream) {
  const float* m = (const float*)d_in[0];
  v4f* out = (v4f*)d_out;
  antecedents_kernel<<<N_SAMPLES, 256, 0, stream>>>(m, out);
}